// Round 7
// baseline (805.594 us; speedup 1.0000x reference)
//
#include <hip/hip_runtime.h>
#include <stdint.h>

#define C_   128
#define H_   128
#define W_   128
#define HW_  (128*128)

typedef unsigned short ushort_t;
typedef __attribute__((ext_vector_type(8)))  short bf16x8;
typedef __attribute__((ext_vector_type(16))) float f32x16;

__device__ __forceinline__ float bf2f(uint32_t u) {
    union { float f; uint32_t i; } v; v.i = u << 16; return v.f;
}
__device__ __forceinline__ uint32_t f2bf(float f) {
    union { float f; uint32_t i; } v; v.f = f;
    uint32_t u = v.i;
    uint32_t r = u + 0x7FFFu + ((u >> 16) & 1u);
    return r >> 16;  // RTNE bf16 bits in low 16
}
__device__ __forceinline__ void async16(const ushort_t* g, void* l) {
    __builtin_amdgcn_global_load_lds(
        (const __attribute__((address_space(1))) unsigned int*)g,
        (__attribute__((address_space(3))) unsigned int*)l, 16, 0, 0);
}

// NHWC-p layout: element (img, h, c, w) at ((img*128+h)*8 + (c>>4))*2048 + w*16 + (c&15)
// attn scale-chunk NCHW: (scale, img, c_local, h, w) at
//   ((scale*16 + img)*32 + c_local)*16384 + h*128 + w   (aliases qw scale windows)

// ---------------------------------------------------------------------------
// prepack conv weights -> MFMA A-fragment-linear order (bf16).
// ---------------------------------------------------------------------------
__global__ __launch_bounds__(256) void prepack_kernel(
    const float* __restrict__ Wo, const float* __restrict__ Wf1,
    const float* __restrict__ Wf2, ushort_t* __restrict__ Wp)
{
    int t = blockIdx.x * 256 + threadIdx.x;          // 0..147455
    const float* W = (blockIdx.y == 0) ? Wo : ((blockIdx.y == 1) ? Wf1 : Wf2);
    ushort_t* dst = Wp + (size_t)blockIdx.y * 147456;
    int j = t & 7, lane = (t >> 3) & 63, f = t >> 9;
    int cot = f & 3, s = (f >> 2) & 1, tap = (f >> 3) % 9, cc = f / 72;
    int co = cot * 32 + (lane & 31);
    int ci = cc * 32 + s * 16 + (lane >> 5) * 8 + j;
    dst[t] = (ushort_t)f2bf(W[((size_t)co * 128 + ci) * 9 + tap]);
}

// ---------------------------------------------------------------------------
// prepack 1x1 qkv weights -> A-fragment-linear (bf16). grid (64, 3).
// ---------------------------------------------------------------------------
__global__ __launch_bounds__(256) void prepack1_kernel(
    const float* __restrict__ Wq, const float* __restrict__ Wk,
    const float* __restrict__ Wv, ushort_t* __restrict__ Wqkv)
{
    int t = blockIdx.x * 256 + threadIdx.x;          // 0..16383
    const float* W = (blockIdx.y == 0) ? Wq : ((blockIdx.y == 1) ? Wk : Wv);
    ushort_t* dst = Wqkv + (size_t)blockIdx.y * 16384;
    int j = t & 7, lane = (t >> 3) & 63, f = t >> 9;  // f 0..31
    int cot = f & 3, s = f >> 2;
    int co = cot * 32 + (lane & 31);
    int ci = s * 16 + (lane >> 5) * 8 + j;
    dst[t] = (ushort_t)f2bf(W[(size_t)co * 128 + ci]);
}

// ---------------------------------------------------------------------------
// NCHW fp32 -> NHWC-p bf16 (for x). grid (128, 16).
// ---------------------------------------------------------------------------
__global__ __launch_bounds__(256) void nchw2nhwc_kernel(
    const float* __restrict__ in, ushort_t* __restrict__ out)
{
    __shared__ ushort_t tile[128 * 136];
    const int img = blockIdx.y, hh = blockIdx.x;
    const int tid = threadIdx.x;
    #pragma unroll
    for (int i = 0; i < 8; ++i) {
        int idx = tid + 256 * i;
        int c = idx >> 4, w8 = (idx & 15) * 8;
        size_t src = ((size_t)img * 128 + c) * (size_t)HW_ + hh * 128 + w8;
        const float4* fp = (const float4*)&in[src];
        float4 f0 = fp[0], f1 = fp[1];
        ushort_t v[8];
        v[0] = (ushort_t)f2bf(f0.x); v[1] = (ushort_t)f2bf(f0.y);
        v[2] = (ushort_t)f2bf(f0.z); v[3] = (ushort_t)f2bf(f0.w);
        v[4] = (ushort_t)f2bf(f1.x); v[5] = (ushort_t)f2bf(f1.y);
        v[6] = (ushort_t)f2bf(f1.z); v[7] = (ushort_t)f2bf(f1.w);
        #pragma unroll
        for (int k = 0; k < 8; ++k) {
            int w = w8 + k;
            int g = (c >> 3) ^ ((w >> 3) & 7);
            tile[w * 136 + g * 8 + (c & 7)] = v[k];
        }
    }
    __syncthreads();
    #pragma unroll
    for (int i = 0; i < 8; ++i) {
        int idx = tid + 256 * i;
        int w = idx >> 4, g = idx & 15;
        int gs = g ^ ((w >> 3) & 7);
        uint4 raw = *(const uint4*)&tile[w * 136 + gs * 8];
        int c8 = g * 8;
        size_t off = (((size_t)(img * 128 + hh)) * 8 + (c8 >> 4)) * 2048 + w * 16 + (c8 & 8);
        *(uint4*)&out[off] = raw;
    }
}

// ---------------------------------------------------------------------------
// attn scale-chunk NCHW (bf16) -> NHWC-p bf16. grid (128, 16).
// ---------------------------------------------------------------------------
__global__ __launch_bounds__(256) void attn2nhwc_kernel(
    const ushort_t* __restrict__ in, ushort_t* __restrict__ out)
{
    __shared__ ushort_t tile[128 * 136];
    const int img = blockIdx.y, hh = blockIdx.x;
    const int tid = threadIdx.x;
    #pragma unroll
    for (int i = 0; i < 8; ++i) {
        int idx = tid + 256 * i;
        int c = idx >> 4, w8 = (idx & 15) * 8;
        size_t src = (((size_t)((c >> 5) * 16 + img)) * 32 + (c & 31)) * (size_t)HW_
                     + hh * 128 + w8;
        uint4 raw = *(const uint4*)&in[src];
        ushort_t v[8];
        v[0] = raw.x & 0xffffu; v[1] = raw.x >> 16;
        v[2] = raw.y & 0xffffu; v[3] = raw.y >> 16;
        v[4] = raw.z & 0xffffu; v[5] = raw.z >> 16;
        v[6] = raw.w & 0xffffu; v[7] = raw.w >> 16;
        #pragma unroll
        for (int k = 0; k < 8; ++k) {
            int w = w8 + k;
            int g = (c >> 3) ^ ((w >> 3) & 7);
            tile[w * 136 + g * 8 + (c & 7)] = v[k];
        }
    }
    __syncthreads();
    #pragma unroll
    for (int i = 0; i < 8; ++i) {
        int idx = tid + 256 * i;
        int w = idx >> 4, g = idx & 15;
        int gs = g ^ ((w >> 3) & 7);
        uint4 raw = *(const uint4*)&tile[w * 136 + gs * 8];
        int c8 = g * 8;
        size_t off = (((size_t)(img * 128 + hh)) * 8 + (c8 >> 4)) * 2048 + w * 16 + (c8 & 8);
        *(uint4*)&out[off] = raw;
    }
}

// ---------------------------------------------------------------------------
// qkv MFMA: NHWC-p input, windowed scatter. Counted-vmcnt double-buffer.
// grid (64, 16, 3), block 256.
// ---------------------------------------------------------------------------
__global__ __launch_bounds__(256, 2) void qkvm_kernel(
    const ushort_t* __restrict__ xn, const ushort_t* __restrict__ Wqkv,
    const float* __restrict__ bq, const float* __restrict__ bk,
    const float* __restrict__ bv,
    ushort_t* __restrict__ qw, ushort_t* __restrict__ kw,
    ushort_t* __restrict__ vw)
{
    __shared__ ushort_t lds[2 * 8192];   // 2 bufs x (2 rows x 128 px x 32 ci), 32 KB
    const int h0 = blockIdx.x * 2, img = blockIdx.y, w3 = blockIdx.z;
    const int tid = threadIdx.x, lane = tid & 63, wv = tid >> 6;
    const int r = wv & 1, wco = (wv >> 1) * 64;
    const ushort_t* Wb = Wqkv + (size_t)w3 * 16384;
    const float* bias = (w3 == 0) ? bq : ((w3 == 1) ? bk : bv);
    ushort_t* outp = (w3 == 0) ? qw : ((w3 == 1) ? kw : vw);
    const int b_ = img >> 2, t_ = img & 3, h = h0 + r;

    f32x16 acc[4][2];
    #pragma unroll
    for (int tm = 0; tm < 4; ++tm)
        #pragma unroll
        for (int tn = 0; tn < 2; ++tn)
            #pragma unroll
            for (int k = 0; k < 16; ++k) acc[tm][tn][k] = 0.f;

    auto STAGE = [&](int cc, int b) {
        #pragma unroll
        for (int kb = wv; kb < 16; kb += 4) {           // 4 loads per wave
            int slot = kb >> 3, px0 = (kb & 7) * 16;
            int px = px0 + (lane >> 2), chunk = lane & 3;
            int g = chunk ^ ((px >> 1) & 3);
            const ushort_t* src = xn
                + (((size_t)(img * 128 + h0 + slot)) * 8 + cc * 2 + (g >> 1)) * 2048
                + px * 16 + (g & 1) * 8;
            async16(src, (char*)lds + b * 16384 + kb * 1024);
        }
    };
    auto COMPUTE = [&](int cc, int b) {
        const ushort_t* sb = lds + b * 8192 + r * 4096;
        #pragma unroll
        for (int s2 = 0; s2 < 2; ++s2) {
            const int s = cc * 2 + s2;
            const int fbase = s * 4 + (wco >> 5);
            bf16x8 a0 = *(const bf16x8*)(Wb + ((size_t)fbase * 64 + lane) * 8);
            bf16x8 a1 = *(const bf16x8*)(Wb + ((size_t)(fbase + 1) * 64 + lane) * 8);
            const int kch = s2 * 2 + (lane >> 5);
            bf16x8 b4[4];
            #pragma unroll
            for (int tm = 0; tm < 4; ++tm) {
                int px = tm * 32 + (lane & 31);
                b4[tm] = *(const bf16x8*)(sb + px * 32 + ((kch ^ ((px >> 1) & 3)) << 3));
            }
            #pragma unroll
            for (int tm = 0; tm < 4; ++tm) {
                acc[tm][0] = __builtin_amdgcn_mfma_f32_32x32x16_bf16(a0, b4[tm], acc[tm][0], 0, 0, 0);
                acc[tm][1] = __builtin_amdgcn_mfma_f32_32x32x16_bf16(a1, b4[tm], acc[tm][1], 0, 0, 0);
            }
        }
    };

    STAGE(0, 0);
    #pragma unroll
    for (int cc = 0; cc < 4; ++cc) {
        if (cc < 3) STAGE(cc + 1, (cc + 1) & 1);
        if (cc < 3) asm volatile("s_waitcnt vmcnt(4)" ::: "memory");
        else        asm volatile("s_waitcnt vmcnt(0)" ::: "memory");
        __builtin_amdgcn_s_barrier();
        __builtin_amdgcn_s_setprio(1);
        COMPUTE(cc, cc & 1);
        __builtin_amdgcn_s_setprio(0);
        __builtin_amdgcn_s_barrier();
    }

    #pragma unroll
    for (int tn = 0; tn < 2; ++tn) {
        const int scale = (wco >> 5) + tn;
        const int lg = 6 - scale, psz = 1 << lg, outn = 128 >> lg;
        const int Dd = 32 << (2 * lg);
        const size_t base = (size_t)scale * 8388608u
            + ((size_t)((b_ * 4 + t_) * outn * outn + (h >> lg) * outn)) * (size_t)Dd;
        const int ph = h & (psz - 1);
        #pragma unroll
        for (int rg = 0; rg < 16; ++rg) {
            int c_local = (rg & 3) + 8 * (rg >> 2) + 4 * (lane >> 5);
            float bb = bias[scale * 32 + c_local];
            size_t K1 = base + (size_t)(((c_local << lg) + ph) << lg);
            #pragma unroll
            for (int tm = 0; tm < 4; ++tm) {
                int px = tm * 32 + (lane & 31);
                int ow = px >> lg, pw = px & (psz - 1);
                outp[K1 + (size_t)ow * Dd + pw] = (ushort_t)f2bf(acc[tm][tn][rg] + bb);
            }
        }
    }
}

// ---------------------------------------------------------------------------
// V transpose per scale: [b][tok][Dd] -> [b][Dd][tok]. 8x8 reg blocks.
// ---------------------------------------------------------------------------
__global__ __launch_bounds__(256) void vtrans_kernel(
    const ushort_t* __restrict__ src, ushort_t* __restrict__ dst, int n, int Dd)
{
    const int b_ = blockIdx.z;
    const int ddb = blockIdx.x * 128, tokb = blockIdx.y * 128;
    const int tid = threadIdx.x;
    const int ti = tid & 15, tj = tid >> 4;
    const int tok0 = tokb + ti * 8, dd0 = ddb + tj * 8;
    if (tok0 >= n) return;
    const ushort_t* s = src + (size_t)b_ * (size_t)n * Dd;
    ushort_t* d = dst + (size_t)b_ * (size_t)n * Dd;
    ushort_t a[8][8];
    #pragma unroll
    for (int e = 0; e < 8; ++e)
        *(uint4*)a[e] = *(const uint4*)&s[(size_t)(tok0 + e) * Dd + dd0];
    #pragma unroll
    for (int q = 0; q < 8; ++q) {
        ushort_t o[8];
        #pragma unroll
        for (int e = 0; e < 8; ++e) o[e] = a[e][q];
        *(uint4*)&d[(size_t)(dd0 + q) * n + tok0] = *(uint4*)o;
    }
}

// ---------------------------------------------------------------------------
// scores MFMA (unchanged).
// ---------------------------------------------------------------------------
template<int CFG>
__global__ __launch_bounds__(256) void scoresm_kernel(
    const ushort_t* __restrict__ qw, const ushort_t* __restrict__ kw,
    float* __restrict__ sc, int lg, int ks_count)
{
    const int outn = 128 >> lg;
    const int n = 4 * outn * outn;
    const int Dd = 32 << (2 * lg);
    const int scale = 6 - lg;
    const size_t base = (size_t)scale * 8388608u;
    const int b_ = blockIdx.z / ks_count, ks = blockIdx.z % ks_count;
    const int DdK = Dd / ks_count;
    const int tid = threadIdx.x, lane = tid & 63, wv = tid >> 6;
    const ushort_t* qb = qw + base + (size_t)b_ * (size_t)n * Dd;
    const ushort_t* kb = kw + base + (size_t)b_ * (size_t)n * Dd;
    float* scb = sc + (size_t)b_ * n * n;
    const float scl = rsqrtf((float)Dd);
    const int koff = (lane >> 5) * 8;
    constexpr int MF = (CFG == 0) ? 2 : 1;
    const int mb = (CFG == 0) ? blockIdx.x * 128 + (wv & 1) * 64
                 : (CFG == 1) ? (wv & 1) * 32 : 0;
    const int nb = (CFG == 0) ? blockIdx.y * 128 + (wv >> 1) * 64
                 : (CFG == 1) ? (wv >> 1) * 32 : 0;

    f32x16 acc[MF][MF];
    #pragma unroll
    for (int i = 0; i < MF; ++i)
        #pragma unroll
        for (int j = 0; j < MF; ++j)
            #pragma unroll
            for (int k = 0; k < 16; ++k) acc[i][j][k] = 0.f;

    int mrow[MF], nrow[MF];
    #pragma unroll
    for (int i = 0; i < MF; ++i) {
        int mr = mb + i * 32 + (lane & 31);
        int nr = nb + i * 32 + (lane & 31);
        if (CFG == 2) { if (mr >= n) mr = n - 1; if (nr >= n) nr = n - 1; }
        mrow[i] = mr; nrow[i] = nr;
    }
    int k0beg = ks * DdK, k0end = k0beg + DdK;
    if (CFG == 2) { int DdW = DdK >> 2; k0beg += wv * DdW; k0end = k0beg + DdW; }

    for (int k0 = k0beg; k0 < k0end; k0 += 16) {
        bf16x8 a[MF], b[MF];
        #pragma unroll
        for (int i = 0; i < MF; ++i)
            a[i] = *(const bf16x8*)(qb + (size_t)mrow[i] * Dd + k0 + koff);
        #pragma unroll
        for (int j = 0; j < MF; ++j)
            b[j] = *(const bf16x8*)(kb + (size_t)nrow[j] * Dd + k0 + koff);
        #pragma unroll
        for (int i = 0; i < MF; ++i)
            #pragma unroll
            for (int j = 0; j < MF; ++j)
                acc[i][j] = __builtin_amdgcn_mfma_f32_32x32x16_bf16(a[i], b[j], acc[i][j], 0, 0, 0);
    }

    #pragma unroll
    for (int i = 0; i < MF; ++i)
        #pragma unroll
        for (int j = 0; j < MF; ++j)
            #pragma unroll
            for (int rg = 0; rg < 16; ++rg) {
                int row = mb + i * 32 + (rg & 3) + 8 * (rg >> 2) + 4 * (lane >> 5);
                int col = nb + j * 32 + (lane & 31);
                if (CFG == 2 && (row >= n || col >= n)) continue;
                float v = acc[i][j][rg] * scl;
                size_t off = (size_t)row * n + col;
                if (ks_count == 1) scb[off] = v;
                else atomicAdd(&scb[off], v);
            }
}

// ---------------------------------------------------------------------------
// softmax rows of sc (fp32) -> pbf (bf16). grid = 4*n, block 256, n<=1024.
// ---------------------------------------------------------------------------
__global__ __launch_bounds__(256) void softmax_kernel(
    const float* __restrict__ sc, ushort_t* __restrict__ pbf, int n)
{
    const int row = blockIdx.x;
    const float* p = sc + (size_t)row * n;
    const int tid = threadIdx.x;
    float v[4];
    #pragma unroll
    for (int j = 0; j < 4; ++j) { int idx = tid + 256 * j; v[j] = (idx < n) ? p[idx] : -3.0e38f; }
    float m = fmaxf(fmaxf(v[0], v[1]), fmaxf(v[2], v[3]));
    #pragma unroll
    for (int off = 32; off >= 1; off >>= 1) m = fmaxf(m, __shfl_xor(m, off));
    __shared__ float red[4];
    const int wid = tid >> 6, lane = tid & 63;
    if (lane == 0) red[wid] = m;
    __syncthreads();
    m = fmaxf(fmaxf(red[0], red[1]), fmaxf(red[2], red[3]));
    float e[4]; float s = 0.f;
    #pragma unroll
    for (int j = 0; j < 4; ++j) { int idx = tid + 256 * j; e[j] = (idx < n) ? __expf(v[j] - m) : 0.f; s += e[j]; }
    #pragma unroll
    for (int off = 32; off >= 1; off >>= 1) s += __shfl_xor(s, off);
    __syncthreads();
    if (lane == 0) red[wid] = s;
    __syncthreads();
    s = red[0] + red[1] + red[2] + red[3];
    float inv = 1.0f / s;
    #pragma unroll
    for (int j = 0; j < 4; ++j) {
        int idx = tid + 256 * j;
        if (idx < n) pbf[(size_t)row * n + idx] = (ushort_t)f2bf(e[j] * inv);
    }
}

// ---------------------------------------------------------------------------
// PV MFMA: y = P V, scatter to scale-chunked NCHW (aliases qw windows).
// ---------------------------------------------------------------------------
template<int CFG>
__global__ __launch_bounds__(256) void pvm_kernel(
    const ushort_t* __restrict__ pbf, const ushort_t* __restrict__ vt,
    ushort_t* __restrict__ attn, int lg)
{
    const int outn = 128 >> lg, psz = 1 << lg;
    const int n = 4 * outn * outn;
    const int Dd = 32 << (2 * lg);
    const int scale = 6 - lg;
    const int b_ = blockIdx.z;
    const int tid = threadIdx.x, lane = tid & 63, wv = tid >> 6;
    const ushort_t* pb = pbf + (size_t)b_ * n * n;
    const ushort_t* vb = vt + (size_t)b_ * (size_t)Dd * n;
    constexpr int MF = (CFG == 0) ? 2 : 1;
    const int mb = (CFG == 0) ? blockIdx.y * 128 + (wv & 1) * 64
                 : (CFG == 1) ? (wv & 1) * 32 : 0;
    const int nb = (CFG == 0) ? blockIdx.x * 128 + (wv >> 1) * 64
                 : (CFG == 1) ? blockIdx.x * 128 + (wv >> 1) * 64
                 : blockIdx.x * 256 + wv * 64;
    const int koff = (lane >> 5) * 8;

    f32x16 acc[MF][2];
    #pragma unroll
    for (int i = 0; i < MF; ++i)
        #pragma unroll
        for (int j = 0; j < 2; ++j)
            #pragma unroll
            for (int k = 0; k < 16; ++k) acc[i][j][k] = 0.f;

    int mr[MF];
    #pragma unroll
    for (int i = 0; i < MF; ++i) {
        int r = mb + i * 32 + (lane & 31);
        if (CFG == 2 && r >= n) r = n - 1;
        mr[i] = r;
    }
    const int nr0 = nb + (lane & 31), nr1 = nr0 + 32;

    for (int k0 = 0; k0 < n; k0 += 16) {
        bf16x8 b0 = *(const bf16x8*)(vb + (size_t)nr0 * n + k0 + koff);
        bf16x8 b1 = *(const bf16x8*)(vb + (size_t)nr1 * n + k0 + koff);
        #pragma unroll
        for (int i = 0; i < MF; ++i) {
            bf16x8 a = *(const bf16x8*)(pb + (size_t)mr[i] * n + k0 + koff);
            acc[i][0] = __builtin_amdgcn_mfma_f32_32x32x16_bf16(a, b0, acc[i][0], 0, 0, 0);
            acc[i][1] = __builtin_amdgcn_mfma_f32_32x32x16_bf16(a, b1, acc[i][1], 0, 0, 0);
        }
    }

    const int lgo = 7 - lg;
    #pragma unroll
    for (int i = 0; i < MF; ++i)
        #pragma unroll
        for (int j = 0; j < 2; ++j)
            #pragma unroll
            for (int rg = 0; rg < 16; ++rg) {
                int tok = mb + i * 32 + (rg & 3) + 8 * (rg >> 2) + 4 * (lane >> 5);
                if (CFG == 2 && tok >= n) continue;
                int dd = nb + j * 32 + (lane & 31);
                int c_local = dd >> (2 * lg);
                int p2 = dd & (psz * psz - 1);
                int ph = p2 >> lg, pw = p2 & (psz - 1);
                int t_ = tok >> (2 * lgo);
                int rem = tok & ((1 << (2 * lgo)) - 1);
                int oh = rem >> lgo, ow = rem & (outn - 1);
                size_t off = (((size_t)(scale * 16 + b_ * 4 + t_) * 32 + c_local) * 128
                              + ((oh << lg) + ph)) * 128 + ((ow << lg) + pw);
                attn[off] = (ushort_t)f2bf(acc[i][j][rg]);
            }
}

// ---------------------------------------------------------------------------
// MFMA implicit-GEMM 3x3 conv v2: XOR-swizzled LDS, counted-vmcnt pipeline,
// XCD-bijective block remap. Wave tile 64px x 32co; block 128px x 64co.
// MODE 0: outn = bf16(res_nhwc + lrelu(acc+bias))        (conv1)
// MODE 1: outn = bf16(lrelu(acc+bias))                   (conv2)
// MODE 2: outf(NCHW f32) = res_nhwc + lrelu(acc+bias)    (conv3, final)
// grid (256, 16), block 256.
// ---------------------------------------------------------------------------
template<int DIL, int MODE>
__global__ __launch_bounds__(256, 4) void conv3n_kernel(
    const ushort_t* __restrict__ in, const ushort_t* __restrict__ Wp,
    const float* __restrict__ bias, const ushort_t* __restrict__ resn,
    float* __restrict__ outf, ushort_t* __restrict__ outn,
    const ushort_t* __restrict__ zp)
{
    // staging: 2 bufs x 16 KB (3 slots x 160 pxi x 16 ci + pad slot) = 32 KB
    // epilogue aliases: [128 px][68 co-pad] = 8704 shorts
    __shared__ ushort_t lds[2 * 8192];
    // XCD-bijective remap: each XCD owns 2 whole images (contiguous h rows)
    const int fid = blockIdx.y * 256 + blockIdx.x;     // 0..4095
    const int nfid = (fid & 7) * 512 + (fid >> 3);
    const int img = nfid >> 8, bx = nfid & 255;
    const int h = bx >> 1, coz = bx & 1;
    const int tid = threadIdx.x, lane = tid & 63, wv = tid >> 6;
    const int pxh = wv & 1, coq = wv >> 1;
    const int cot = coz * 2 + coq;          // 32-co tile index (matches prepack)
    const int kch = lane >> 5;

    f32x16 acc[2];
    #pragma unroll
    for (int i = 0; i < 2; ++i)
        #pragma unroll
        for (int k = 0; k < 16; ++k) acc[i][k] = 0.f;

    auto STAGE = [&](int p, int b) {
        #pragma unroll
        for (int kb = wv; kb < 16; kb += 4) {      // exactly 4 loads per wave
            const ushort_t* src;
            if (kb == 15) {
                src = zp + lane * 8;               // pad load (uniform vmcnt)
            } else {
                int slot = kb / 5, pg = kb % 5;
                int pxi = pg * 32 + (lane >> 1);
                int wc = pxi - 16;
                int ir = h + (slot - 1) * DIL;
                int cg = (lane & 1) ^ ((pxi >> 2) & 1);   // pre-swizzled source
                if (wc >= 0 && wc < 128 && ir >= 0 && ir < 128)
                    src = in + (((size_t)(img * 128 + ir)) * 8 + p) * 2048 + wc * 16 + cg * 8;
                else
                    src = zp + lane * 8;
            }
            async16(src, (char*)lds + b * 16384 + kb * 1024);
        }
    };
    auto COMPUTE = [&](int p, int b) {
        const ushort_t* bbuf = lds + b * 8192;
        #pragma unroll
        for (int tap = 0; tap < 9; ++tap) {
            const int slot = tap / 3, tc = tap % 3;
            const int fbase = (((p >> 1) * 9 + tap) * 2 + (p & 1)) * 4 + cot;
            bf16x8 a = *(const bf16x8*)(Wp + ((size_t)fbase * 64 + lane) * 8);
            #pragma unroll
            for (int i = 0; i < 2; ++i) {
                int pxi = pxh * 64 + i * 32 + (lane & 31) + (tc - 1) * DIL + 16;
                int s = kch ^ ((pxi >> 2) & 1);            // swizzled read
                bf16x8 bv = *(const bf16x8*)(bbuf + slot * 2560 + pxi * 16 + s * 8);
                acc[i] = __builtin_amdgcn_mfma_f32_32x32x16_bf16(a, bv, acc[i], 0, 0, 0);
            }
        }
    };

    STAGE(0, 0);
    #pragma unroll
    for (int p = 0; p < 8; ++p) {
        if (p < 7) STAGE(p + 1, (p + 1) & 1);      // prefetch stays in flight
        if (p < 7) asm volatile("s_waitcnt vmcnt(4)" ::: "memory");
        else       asm volatile("s_waitcnt vmcnt(0)" ::: "memory");
        __builtin_amdgcn_s_barrier();              // all waves' phase-p loads done
        __builtin_amdgcn_s_setprio(1);
        COMPUTE(p, p & 1);
        __builtin_amdgcn_s_setprio(0);
        __builtin_amdgcn_s_barrier();              // reads done before overwrite
    }
    __syncthreads();

    // ---- epilogue (lds reused as [128 px][68] bf16 tile of this 64-co half)
    if (MODE == 0 || MODE == 2) {
        for (int u = tid; u < 1024; u += 256) {
            int px = u >> 3, lc8 = (u & 7) * 8;
            size_t soff = (((size_t)(img * 128 + h)) * 8 + coz * 4 + (lc8 >> 4)) * 2048
                          + px * 16 + (lc8 & 8);
            uint4 raw = *(const uint4*)&resn[soff];
            *(uint4*)&lds[px * 68 + lc8] = raw;
        }
        __syncthreads();
    }
    #pragma unroll
    for (int i = 0; i < 2; ++i)
        #pragma unroll
        for (int rg = 0; rg < 16; ++rg) {
            int lc = coq * 32 + (rg & 3) + 8 * (rg >> 2) + 4 * kch;  // 0..63
            int px = pxh * 64 + i * 32 + (lane & 31);
            float v = acc[i][rg] + bias[coz * 64 + lc];
            v = (v >= 0.f) ? v : 0.2f * v;
            if (MODE == 0) {
                float w = bf2f(lds[px * 68 + lc]) + v;
                lds[px * 68 + lc] = (ushort_t)f2bf(w);
            } else if (MODE == 1) {
                lds[px * 68 + lc] = (ushort_t)f2bf(v);
            } else {
                float w = bf2f(lds[px * 68 + lc]) + v;
                outf[(((size_t)(img * 128 + coz * 64 + lc)) * 128 + h) * 128 + px] = w;
            }
        }
    if (MODE == 0 || MODE == 1) {
        __syncthreads();
        for (int u = tid; u < 1024; u += 256) {
            int px = u >> 3, lc8 = (u & 7) * 8;
            uint4 raw = *(const uint4*)&lds[px * 68 + lc8];
            size_t doff = (((size_t)(img * 128 + h)) * 8 + coz * 4 + (lc8 >> 4)) * 2048
                          + px * 16 + (lc8 & 8);
            *(uint4*)&outn[doff] = raw;
        }
    }
}

// ---------------------------------------------------------------------------
extern "C" void kernel_launch(void* const* d_in, const int* in_sizes, int n_in,
                              void* d_out, int out_size, void* d_ws, size_t ws_size,
                              hipStream_t stream)
{
    const float* x   = (const float*)d_in[0];
    const float* Wq  = (const float*)d_in[1];
    const float* bq  = (const float*)d_in[2];
    const float* Wk  = (const float*)d_in[3];
    const float* bk  = (const float*)d_in[4];
    const float* Wv  = (const float*)d_in[5];
    const float* bv  = (const float*)d_in[6];
    const float* Wo  = (const float*)d_in[7];
    const float* bo  = (const float*)d_in[8];
    const float* Wf1 = (const float*)d_in[9];
    const float* bf1 = (const float*)d_in[10];
    const float* Wf2 = (const float*)d_in[11];
    const float* bf2 = (const float*)d_in[12];
    float* out = (float*)d_out;
    char* ws = (char*)d_ws;
    const size_t MB = 1048576ull;
    ushort_t* qw   = (ushort_t*)(ws);                 // 64 MB; attn chunks alias; later ff1n
    ushort_t* kw   = (ushort_t*)(ws + 64 * MB);       // 64 MB; later attn NHWC-p
    ushort_t* vw   = (ushort_t*)(ws + 128 * MB);      // 64 MB; later x1n NHWC-p
    ushort_t* xn   = (ushort_t*)(ws + 192 * MB);      // 64 MB; x NHWC-p (lives to conv1)
    float*    sc   = (float*)   (ws + 256 * MB);      // 16 MB
    ushort_t* Wp   = (ushort_t*)(ws + 273 * MB);      // 864 KB
    ushort_t* Wqkv = (ushort_t*)(ws + 274 * MB);      // 96 KB
    ushort_t* zp   = (ushort_t*)(ws + 275 * MB);      // 1 KB zeros
    ushort_t* pbf  = (ushort_t*)(ws + 276 * MB);      // 8 MB
    ushort_t* vt   = (ushort_t*)(ws + 285 * MB);      // 16 MB
    ushort_t* attnc = qw;    // attn scale-chunk NCHW (aliases qw dead windows)
    ushort_t* nhwc  = kw;    // attn NHWC-p (kw dead after scores s3)
    ushort_t* x1n   = vw;    // x1 NHWC-p (vw dead after vtrans s3)
    ushort_t* ff1n  = qw;    // ff1 NHWC-p (qw/attnc dead after attn2nhwc+conv1)

    hipMemsetAsync(zp, 0, 1024, stream);
    prepack_kernel<<<dim3(576, 3), 256, 0, stream>>>(Wo, Wf1, Wf2, Wp);
    prepack1_kernel<<<dim3(64, 3), 256, 0, stream>>>(Wq, Wk, Wv, Wqkv);

    // 1) x -> NHWC-p bf16, then q/k/v MFMA -> windowed layouts
    nchw2nhwc_kernel<<<dim3(128, 16), 256, 0, stream>>>(x, xn);
    qkvm_kernel<<<dim3(64, 16, 3), 256, 0, stream>>>(xn, Wqkv, bq, bk, bv, qw, kw, vw);

    // 2) per-scale attention (pvm writes scale-chunk NCHW into qw dead windows)
    // s0: n=16, Dd=131072
    vtrans_kernel<<<dim3(1024, 1, 4), 256, 0, stream>>>(vw + 0 * 8388608u, vt, 16, 131072);
    hipMemsetAsync(sc, 0, (size_t)4 * 16 * 16 * 4, stream);
    scoresm_kernel<2><<<dim3(1, 1, 256), 256, 0, stream>>>(qw, kw, sc, 6, 64);
    softmax_kernel<<<dim3(64), 256, 0, stream>>>(sc, pbf, 16);
    pvm_kernel<2><<<dim3(512, 1, 4), 256, 0, stream>>>(pbf, vt, attnc, 6);
    // s1: n=64, Dd=32768
    vtrans_kernel<<<dim3(256, 1, 4), 256, 0, stream>>>(vw + 1 * 8388608u, vt, 64, 32768);
    hipMemsetAsync(sc, 0, (size_t)4 * 64 * 64 * 4, stream);
    scoresm_kernel<1><<<dim3(1, 1, 256), 256, 0, stream>>>(qw, kw, sc, 5, 64);
    softmax_kernel<<<dim3(256), 256, 0, stream>>>(sc, pbf, 64);
    pvm_kernel<1><<<dim3(256, 1, 4), 256, 0, stream>>>(pbf, vt, attnc, 5);
    // s2: n=256, Dd=8192
    vtrans_kernel<<<dim3(64, 2, 4), 256, 0, stream>>>(vw + 2 * 8388608u, vt, 256, 8192);
    hipMemsetAsync(sc, 0, (size_t)4 * 256 * 256 * 4, stream);
    scoresm_kernel<0><<<dim3(2, 2, 64), 256, 0, stream>>>(qw, kw, sc, 4, 16);
    softmax_kernel<<<dim3(1024), 256, 0, stream>>>(sc, pbf, 256);
    pvm_kernel<0><<<dim3(64, 2, 4), 256, 0, stream>>>(pbf, vt, attnc, 4);
    // s3: n=1024, Dd=2048
    vtrans_kernel<<<dim3(16, 8, 4), 256, 0, stream>>>(vw + 3 * 8388608u, vt, 1024, 2048);
    scoresm_kernel<0><<<dim3(8, 8, 4), 256, 0, stream>>>(qw, kw, sc, 3, 1);
    softmax_kernel<<<dim3(4096), 256, 0, stream>>>(sc, pbf, 1024);
    pvm_kernel<0><<<dim3(16, 8, 4), 256, 0, stream>>>(pbf, vt, attnc, 3);

    // 3) attn chunks -> NHWC-p (into kw region)
    attn2nhwc_kernel<<<dim3(128, 16), 256, 0, stream>>>(attnc, nhwc);
    // 4) x1 = x + lrelu(conv3x3(attn)) -> x1n NHWC-p bf16 only
    conv3n_kernel<1, 0><<<dim3(256, 16), 256, 0, stream>>>(nhwc, Wp, bo, xn, nullptr, x1n, zp);
    // 5) ff1 = lrelu(conv3x3 dil2(x1)) -> ff1n NHWC-p bf16
    conv3n_kernel<2, 1><<<dim3(256, 16), 256, 0, stream>>>(x1n, Wp + 147456, bf1, nullptr, nullptr, ff1n, zp);
    // 6) out = x1 + lrelu(conv3x3(ff1)) -> d_out fp32 NCHW (pure write)
    conv3n_kernel<1, 2><<<dim3(256, 16), 256, 0, stream>>>(ff1n, Wp + 2 * 147456, bf2, x1n, out, nullptr, zp);
}

// Round 8
// 754.980 us; speedup vs baseline: 1.0670x; 1.0670x over previous
//
#include <hip/hip_runtime.h>
#include <stdint.h>

#define C_   128
#define H_   128
#define W_   128
#define HW_  (128*128)

// sc/pbf per-scale element offsets (s3 first, then s2, s1, s0)
#define SC_OFF3 0
#define SC_OFF2 4194304
#define SC_OFF1 4456448
#define SC_OFF0 4472832
#define SC_TOT  4473856

typedef unsigned short ushort_t;
typedef __attribute__((ext_vector_type(8)))  short bf16x8;
typedef __attribute__((ext_vector_type(16))) float f32x16;

__device__ __forceinline__ float bf2f(uint32_t u) {
    union { float f; uint32_t i; } v; v.i = u << 16; return v.f;
}
__device__ __forceinline__ uint32_t f2bf(float f) {
    union { float f; uint32_t i; } v; v.f = f;
    uint32_t u = v.i;
    uint32_t r = u + 0x7FFFu + ((u >> 16) & 1u);
    return r >> 16;  // RTNE bf16 bits in low 16
}
__device__ __forceinline__ void async16(const ushort_t* g, void* l) {
    __builtin_amdgcn_global_load_lds(
        (const __attribute__((address_space(1))) unsigned int*)g,
        (__attribute__((address_space(3))) unsigned int*)l, 16, 0, 0);
}

// NHWC-p layout: element (img, h, c, w) at ((img*128+h)*8 + (c>>4))*2048 + w*16 + (c&15)
// attn scale-chunk NCHW: ((scale*16+img)*32 + c_local)*16384 + h*128 + w (aliases qw)
// V stored transposed per scale: vw + scale*8388608 + (b*Dd + dd)*n + tok

// ---------------------------------------------------------------------------
// prepack conv weights -> MFMA A-fragment-linear order (bf16).
// ---------------------------------------------------------------------------
__global__ __launch_bounds__(256) void prepack_kernel(
    const float* __restrict__ Wo, const float* __restrict__ Wf1,
    const float* __restrict__ Wf2, ushort_t* __restrict__ Wp)
{
    int t = blockIdx.x * 256 + threadIdx.x;          // 0..147455
    const float* W = (blockIdx.y == 0) ? Wo : ((blockIdx.y == 1) ? Wf1 : Wf2);
    ushort_t* dst = Wp + (size_t)blockIdx.y * 147456;
    int j = t & 7, lane = (t >> 3) & 63, f = t >> 9;
    int cot = f & 3, s = (f >> 2) & 1, tap = (f >> 3) % 9, cc = f / 72;
    int co = cot * 32 + (lane & 31);
    int ci = cc * 32 + s * 16 + (lane >> 5) * 8 + j;
    dst[t] = (ushort_t)f2bf(W[((size_t)co * 128 + ci) * 9 + tap]);
}

// ---------------------------------------------------------------------------
// prepack 1x1 qkv weights -> A-fragment-linear (bf16). grid (64, 3).
// ---------------------------------------------------------------------------
__global__ __launch_bounds__(256) void prepack1_kernel(
    const float* __restrict__ Wq, const float* __restrict__ Wk,
    const float* __restrict__ Wv, ushort_t* __restrict__ Wqkv)
{
    int t = blockIdx.x * 256 + threadIdx.x;          // 0..16383
    const float* W = (blockIdx.y == 0) ? Wq : ((blockIdx.y == 1) ? Wk : Wv);
    ushort_t* dst = Wqkv + (size_t)blockIdx.y * 16384;
    int j = t & 7, lane = (t >> 3) & 63, f = t >> 9;  // f 0..31
    int cot = f & 3, s = f >> 2;
    int co = cot * 32 + (lane & 31);
    int ci = s * 16 + (lane >> 5) * 8 + j;
    dst[t] = (ushort_t)f2bf(W[(size_t)co * 128 + ci]);
}

// ---------------------------------------------------------------------------
// NCHW fp32 -> NHWC-p bf16 (for x). grid (128, 16).
// ---------------------------------------------------------------------------
__global__ __launch_bounds__(256) void nchw2nhwc_kernel(
    const float* __restrict__ in, ushort_t* __restrict__ out)
{
    __shared__ ushort_t tile[128 * 136];
    const int img = blockIdx.y, hh = blockIdx.x;
    const int tid = threadIdx.x;
    #pragma unroll
    for (int i = 0; i < 8; ++i) {
        int idx = tid + 256 * i;
        int c = idx >> 4, w8 = (idx & 15) * 8;
        size_t src = ((size_t)img * 128 + c) * (size_t)HW_ + hh * 128 + w8;
        const float4* fp = (const float4*)&in[src];
        float4 f0 = fp[0], f1 = fp[1];
        ushort_t v[8];
        v[0] = (ushort_t)f2bf(f0.x); v[1] = (ushort_t)f2bf(f0.y);
        v[2] = (ushort_t)f2bf(f0.z); v[3] = (ushort_t)f2bf(f0.w);
        v[4] = (ushort_t)f2bf(f1.x); v[5] = (ushort_t)f2bf(f1.y);
        v[6] = (ushort_t)f2bf(f1.z); v[7] = (ushort_t)f2bf(f1.w);
        #pragma unroll
        for (int k = 0; k < 8; ++k) {
            int w = w8 + k;
            int g = (c >> 3) ^ ((w >> 3) & 7);
            tile[w * 136 + g * 8 + (c & 7)] = v[k];
        }
    }
    __syncthreads();
    #pragma unroll
    for (int i = 0; i < 8; ++i) {
        int idx = tid + 256 * i;
        int w = idx >> 4, g = idx & 15;
        int gs = g ^ ((w >> 3) & 7);
        uint4 raw = *(const uint4*)&tile[w * 136 + gs * 8];
        int c8 = g * 8;
        size_t off = (((size_t)(img * 128 + hh)) * 8 + (c8 >> 4)) * 2048 + w * 16 + (c8 & 8);
        *(uint4*)&out[off] = raw;
    }
}

// ---------------------------------------------------------------------------
// attn scale-chunk NCHW (bf16) -> NHWC-p bf16. grid (128, 16).
// ---------------------------------------------------------------------------
__global__ __launch_bounds__(256) void attn2nhwc_kernel(
    const ushort_t* __restrict__ in, ushort_t* __restrict__ out)
{
    __shared__ ushort_t tile[128 * 136];
    const int img = blockIdx.y, hh = blockIdx.x;
    const int tid = threadIdx.x;
    #pragma unroll
    for (int i = 0; i < 8; ++i) {
        int idx = tid + 256 * i;
        int c = idx >> 4, w8 = (idx & 15) * 8;
        size_t src = (((size_t)((c >> 5) * 16 + img)) * 32 + (c & 31)) * (size_t)HW_
                     + hh * 128 + w8;
        uint4 raw = *(const uint4*)&in[src];
        ushort_t v[8];
        v[0] = raw.x & 0xffffu; v[1] = raw.x >> 16;
        v[2] = raw.y & 0xffffu; v[3] = raw.y >> 16;
        v[4] = raw.z & 0xffffu; v[5] = raw.z >> 16;
        v[6] = raw.w & 0xffffu; v[7] = raw.w >> 16;
        #pragma unroll
        for (int k = 0; k < 8; ++k) {
            int w = w8 + k;
            int g = (c >> 3) ^ ((w >> 3) & 7);
            tile[w * 136 + g * 8 + (c & 7)] = v[k];
        }
    }
    __syncthreads();
    #pragma unroll
    for (int i = 0; i < 8; ++i) {
        int idx = tid + 256 * i;
        int w = idx >> 4, g = idx & 15;
        int gs = g ^ ((w >> 3) & 7);
        uint4 raw = *(const uint4*)&tile[w * 136 + gs * 8];
        int c8 = g * 8;
        size_t off = (((size_t)(img * 128 + hh)) * 8 + (c8 >> 4)) * 2048 + w * 16 + (c8 & 8);
        *(uint4*)&out[off] = raw;
    }
}

// ---------------------------------------------------------------------------
// qkv MFMA: NHWC-p input. Q/K -> windowed layout; V -> transposed [Dd][tok].
// Weight regs preloaded BEFORE stage so vmcnt FIFO never drains the prefetch.
// grid (64, 16, 3), block 256.
// ---------------------------------------------------------------------------
__global__ __launch_bounds__(256, 2) void qkvm_kernel(
    const ushort_t* __restrict__ xn, const ushort_t* __restrict__ Wqkv,
    const float* __restrict__ bq, const float* __restrict__ bk,
    const float* __restrict__ bv,
    ushort_t* __restrict__ qw, ushort_t* __restrict__ kw,
    ushort_t* __restrict__ vw)
{
    __shared__ ushort_t lds[2 * 8192];
    const int h0 = blockIdx.x * 2, img = blockIdx.y, w3 = blockIdx.z;
    const int tid = threadIdx.x, lane = tid & 63, wv = tid >> 6;
    const int r = wv & 1, wco = (wv >> 1) * 64;
    const ushort_t* Wb = Wqkv + (size_t)w3 * 16384;
    const float* bias = (w3 == 0) ? bq : ((w3 == 1) ? bk : bv);
    ushort_t* outp = (w3 == 0) ? qw : ((w3 == 1) ? kw : vw);
    const int b_ = img >> 2, t_ = img & 3, h = h0 + r;

    f32x16 acc[4][2];
    #pragma unroll
    for (int tm = 0; tm < 4; ++tm)
        #pragma unroll
        for (int tn = 0; tn < 2; ++tn)
            #pragma unroll
            for (int k = 0; k < 16; ++k) acc[tm][tn][k] = 0.f;

    auto STAGE = [&](int cc, int b) {
        #pragma unroll
        for (int kb = wv; kb < 16; kb += 4) {
            int slot = kb >> 3, px0 = (kb & 7) * 16;
            int px = px0 + (lane >> 2), chunk = lane & 3;
            int g = chunk ^ ((px >> 1) & 3);
            const ushort_t* src = xn
                + (((size_t)(img * 128 + h0 + slot)) * 8 + cc * 2 + (g >> 1)) * 2048
                + px * 16 + (g & 1) * 8;
            async16(src, (char*)lds + b * 16384 + kb * 1024);
        }
    };

    STAGE(0, 0);
    #pragma unroll
    for (int cc = 0; cc < 4; ++cc) {
        bf16x8 wa[2][2];
        #pragma unroll
        for (int s2 = 0; s2 < 2; ++s2) {
            int fbase = (cc * 2 + s2) * 4 + (wco >> 5);
            wa[s2][0] = *(const bf16x8*)(Wb + ((size_t)fbase * 64 + lane) * 8);
            wa[s2][1] = *(const bf16x8*)(Wb + ((size_t)(fbase + 1) * 64 + lane) * 8);
        }
        asm volatile("" ::: "memory");
        if (cc < 3) STAGE(cc + 1, (cc + 1) & 1);
        if (cc < 3) asm volatile("s_waitcnt vmcnt(8)" ::: "memory");
        else        asm volatile("s_waitcnt vmcnt(4)" ::: "memory");
        __builtin_amdgcn_s_barrier();
        __builtin_amdgcn_s_setprio(1);
        const ushort_t* sb = lds + (cc & 1) * 8192 + r * 4096;
        #pragma unroll
        for (int s2 = 0; s2 < 2; ++s2) {
            const int kch = s2 * 2 + (lane >> 5);
            #pragma unroll
            for (int tm = 0; tm < 4; ++tm) {
                int px = tm * 32 + (lane & 31);
                bf16x8 bvf = *(const bf16x8*)(sb + px * 32 + ((kch ^ ((px >> 1) & 3)) << 3));
                acc[tm][0] = __builtin_amdgcn_mfma_f32_32x32x16_bf16(wa[s2][0], bvf, acc[tm][0], 0, 0, 0);
                acc[tm][1] = __builtin_amdgcn_mfma_f32_32x32x16_bf16(wa[s2][1], bvf, acc[tm][1], 0, 0, 0);
            }
        }
        __builtin_amdgcn_s_setprio(0);
        __builtin_amdgcn_s_barrier();
    }

    #pragma unroll
    for (int tn = 0; tn < 2; ++tn) {
        const int scale = (wco >> 5) + tn;
        const int lg = 6 - scale, psz = 1 << lg, outn = 128 >> lg;
        const int Dd = 32 << (2 * lg);
        const int n = 4 * outn * outn;
        const int oh = h >> lg, ph = h & (psz - 1);
        if (w3 == 2) {
            // V: transposed layout  vw + scale*8M + (b*Dd + dd)*n + tok
            const size_t baseV = (size_t)scale * 8388608u + (size_t)b_ * (size_t)Dd * n;
            const int ntb = t_ * outn * outn + oh * outn;
            #pragma unroll
            for (int rg = 0; rg < 16; ++rg) {
                int c_local = (rg & 3) + 8 * (rg >> 2) + 4 * (lane >> 5);
                float bb = bias[scale * 32 + c_local];
                int ddb = ((c_local << lg) + ph) << lg;
                #pragma unroll
                for (int tm = 0; tm < 4; ++tm) {
                    int px = tm * 32 + (lane & 31);
                    int ow = px >> lg, pw = px & (psz - 1);
                    outp[baseV + (size_t)(ddb + pw) * n + ntb + ow] =
                        (ushort_t)f2bf(acc[tm][tn][rg] + bb);
                }
            }
        } else {
            const size_t base = (size_t)scale * 8388608u
                + ((size_t)((b_ * 4 + t_) * outn * outn + oh * outn)) * (size_t)Dd;
            #pragma unroll
            for (int rg = 0; rg < 16; ++rg) {
                int c_local = (rg & 3) + 8 * (rg >> 2) + 4 * (lane >> 5);
                float bb = bias[scale * 32 + c_local];
                size_t K1 = base + (size_t)(((c_local << lg) + ph) << lg);
                #pragma unroll
                for (int tm = 0; tm < 4; ++tm) {
                    int px = tm * 32 + (lane & 31);
                    int ow = px >> lg, pw = px & (psz - 1);
                    outp[K1 + (size_t)ow * Dd + pw] = (ushort_t)f2bf(acc[tm][tn][rg] + bb);
                }
            }
        }
    }
}

// ---------------------------------------------------------------------------
// scores device body (parameterized, from proven scoresm_kernel).
// ---------------------------------------------------------------------------
template<int CFG>
__device__ __forceinline__ void scores_dev(
    const ushort_t* __restrict__ qw, const ushort_t* __restrict__ kw,
    float* __restrict__ sc_s, int lg, int ks_count, int bx, int by, int b_, int ks)
{
    const int outn = 128 >> lg;
    const int n = 4 * outn * outn;
    const int Dd = 32 << (2 * lg);
    const int scale = 6 - lg;
    const size_t base = (size_t)scale * 8388608u;
    const int DdK = Dd / ks_count;
    const int tid = threadIdx.x, lane = tid & 63, wv = tid >> 6;
    const ushort_t* qb = qw + base + (size_t)b_ * (size_t)n * Dd;
    const ushort_t* kb = kw + base + (size_t)b_ * (size_t)n * Dd;
    float* scb = sc_s + (size_t)b_ * n * n;
    const float scl = rsqrtf((float)Dd);
    const int koff = (lane >> 5) * 8;
    constexpr int MF = (CFG == 0) ? 2 : 1;
    const int mb = (CFG == 0) ? bx * 128 + (wv & 1) * 64
                 : (CFG == 1) ? (wv & 1) * 32 : 0;
    const int nb = (CFG == 0) ? by * 128 + (wv >> 1) * 64
                 : (CFG == 1) ? (wv >> 1) * 32 : 0;

    f32x16 acc[MF][MF];
    #pragma unroll
    for (int i = 0; i < MF; ++i)
        #pragma unroll
        for (int j = 0; j < MF; ++j)
            #pragma unroll
            for (int k = 0; k < 16; ++k) acc[i][j][k] = 0.f;

    int mrow[MF], nrow[MF];
    #pragma unroll
    for (int i = 0; i < MF; ++i) {
        int mr = mb + i * 32 + (lane & 31);
        int nr = nb + i * 32 + (lane & 31);
        if (CFG == 2) { if (mr >= n) mr = n - 1; if (nr >= n) nr = n - 1; }
        mrow[i] = mr; nrow[i] = nr;
    }
    int k0beg = ks * DdK, k0end = k0beg + DdK;
    if (CFG == 2) { int DdW = DdK >> 2; k0beg += wv * DdW; k0end = k0beg + DdW; }

    for (int k0 = k0beg; k0 < k0end; k0 += 16) {
        bf16x8 a[MF], b[MF];
        #pragma unroll
        for (int i = 0; i < MF; ++i)
            a[i] = *(const bf16x8*)(qb + (size_t)mrow[i] * Dd + k0 + koff);
        #pragma unroll
        for (int j = 0; j < MF; ++j)
            b[j] = *(const bf16x8*)(kb + (size_t)nrow[j] * Dd + k0 + koff);
        #pragma unroll
        for (int i = 0; i < MF; ++i)
            #pragma unroll
            for (int j = 0; j < MF; ++j)
                acc[i][j] = __builtin_amdgcn_mfma_f32_32x32x16_bf16(a[i], b[j], acc[i][j], 0, 0, 0);
    }

    #pragma unroll
    for (int i = 0; i < MF; ++i)
        #pragma unroll
        for (int j = 0; j < MF; ++j)
            #pragma unroll
            for (int rg = 0; rg < 16; ++rg) {
                int row = mb + i * 32 + (rg & 3) + 8 * (rg >> 2) + 4 * (lane >> 5);
                int col = nb + j * 32 + (lane & 31);
                if (CFG == 2 && (row >= n || col >= n)) continue;
                float v = acc[i][j][rg] * scl;
                size_t off = (size_t)row * n + col;
                if (ks_count == 1) scb[off] = v;
                else atomicAdd(&scb[off], v);
            }
}

// fused: 1024 blocks (256 per scale)
__global__ __launch_bounds__(256) void scores_all_kernel(
    const ushort_t* __restrict__ qw, const ushort_t* __restrict__ kw,
    float* __restrict__ sc)
{
    const int bid = blockIdx.x;
    const int scale = bid >> 8, sid = bid & 255;
    if (scale == 0)
        scores_dev<2>(qw, kw, sc + SC_OFF0, 6, 64, 0, 0, sid >> 6, sid & 63);
    else if (scale == 1)
        scores_dev<1>(qw, kw, sc + SC_OFF1, 5, 64, 0, 0, sid >> 6, sid & 63);
    else if (scale == 2)
        scores_dev<0>(qw, kw, sc + SC_OFF2, 4, 16, sid & 1, (sid >> 1) & 1, (sid >> 2) >> 4, (sid >> 2) & 15);
    else
        scores_dev<0>(qw, kw, sc + SC_OFF3, 3, 1, sid & 7, (sid >> 3) & 7, sid >> 6, 0);
}

// ---------------------------------------------------------------------------
// softmax fused over all scales. grid 5440.
// ---------------------------------------------------------------------------
__global__ __launch_bounds__(256) void softmax_all_kernel(
    const float* __restrict__ sc, ushort_t* __restrict__ pbf)
{
    const int bid = blockIdx.x;
    int n; size_t off; int row;
    if (bid < 64)        { n = 16;   row = bid;        off = SC_OFF0; }
    else if (bid < 320)  { n = 64;   row = bid - 64;   off = SC_OFF1; }
    else if (bid < 1344) { n = 256;  row = bid - 320;  off = SC_OFF2; }
    else                 { n = 1024; row = bid - 1344; off = SC_OFF3; }
    const float* p = sc + off + (size_t)row * n;
    ushort_t* q = pbf + off + (size_t)row * n;
    const int tid = threadIdx.x;
    float v[4];
    #pragma unroll
    for (int j = 0; j < 4; ++j) { int idx = tid + 256 * j; v[j] = (idx < n) ? p[idx] : -3.0e38f; }
    float m = fmaxf(fmaxf(v[0], v[1]), fmaxf(v[2], v[3]));
    #pragma unroll
    for (int off2 = 32; off2 >= 1; off2 >>= 1) m = fmaxf(m, __shfl_xor(m, off2));
    __shared__ float red[4];
    const int wid = tid >> 6, lane = tid & 63;
    if (lane == 0) red[wid] = m;
    __syncthreads();
    m = fmaxf(fmaxf(red[0], red[1]), fmaxf(red[2], red[3]));
    float e[4]; float s = 0.f;
    #pragma unroll
    for (int j = 0; j < 4; ++j) { int idx = tid + 256 * j; e[j] = (idx < n) ? __expf(v[j] - m) : 0.f; s += e[j]; }
    #pragma unroll
    for (int off2 = 32; off2 >= 1; off2 >>= 1) s += __shfl_xor(s, off2);
    __syncthreads();
    if (lane == 0) red[wid] = s;
    __syncthreads();
    s = red[0] + red[1] + red[2] + red[3];
    float inv = 1.0f / s;
    #pragma unroll
    for (int j = 0; j < 4; ++j) {
        int idx = tid + 256 * j;
        if (idx < n) q[idx] = (ushort_t)f2bf(e[j] * inv);
    }
}

// ---------------------------------------------------------------------------
// PV device body; V read from vw (transposed layout). Writes attnc chunks.
// ---------------------------------------------------------------------------
template<int CFG>
__device__ __forceinline__ void pvm_dev(
    const ushort_t* __restrict__ pbf_s, const ushort_t* __restrict__ vw,
    ushort_t* __restrict__ attn, int lg, int bx, int by, int b_)
{
    const int outn = 128 >> lg, psz = 1 << lg;
    const int n = 4 * outn * outn;
    const int Dd = 32 << (2 * lg);
    const int scale = 6 - lg;
    const int tid = threadIdx.x, lane = tid & 63, wv = tid >> 6;
    const ushort_t* pb = pbf_s + (size_t)b_ * n * n;
    const ushort_t* vb = vw + (size_t)scale * 8388608u + (size_t)b_ * (size_t)Dd * n;
    constexpr int MF = (CFG == 0) ? 2 : 1;
    const int mb = (CFG == 0) ? by * 128 + (wv & 1) * 64
                 : (CFG == 1) ? (wv & 1) * 32 : 0;
    const int nb = (CFG == 0) ? bx * 128 + (wv >> 1) * 64
                 : (CFG == 1) ? bx * 128 + (wv >> 1) * 64
                 : bx * 256 + wv * 64;
    const int koff = (lane >> 5) * 8;

    f32x16 acc[MF][2];
    #pragma unroll
    for (int i = 0; i < MF; ++i)
        #pragma unroll
        for (int j = 0; j < 2; ++j)
            #pragma unroll
            for (int k = 0; k < 16; ++k) acc[i][j][k] = 0.f;

    int mr[MF];
    #pragma unroll
    for (int i = 0; i < MF; ++i) {
        int r = mb + i * 32 + (lane & 31);
        if (CFG == 2 && r >= n) r = n - 1;
        mr[i] = r;
    }
    const int nr0 = nb + (lane & 31), nr1 = nr0 + 32;

    for (int k0 = 0; k0 < n; k0 += 16) {
        bf16x8 b0 = *(const bf16x8*)(vb + (size_t)nr0 * n + k0 + koff);
        bf16x8 b1 = *(const bf16x8*)(vb + (size_t)nr1 * n + k0 + koff);
        #pragma unroll
        for (int i = 0; i < MF; ++i) {
            bf16x8 a = *(const bf16x8*)(pb + (size_t)mr[i] * n + k0 + koff);
            acc[i][0] = __builtin_amdgcn_mfma_f32_32x32x16_bf16(a, b0, acc[i][0], 0, 0, 0);
            acc[i][1] = __builtin_amdgcn_mfma_f32_32x32x16_bf16(a, b1, acc[i][1], 0, 0, 0);
        }
    }

    const int lgo = 7 - lg;
    #pragma unroll
    for (int i = 0; i < MF; ++i)
        #pragma unroll
        for (int j = 0; j < 2; ++j)
            #pragma unroll
            for (int rg = 0; rg < 16; ++rg) {
                int tok = mb + i * 32 + (rg & 3) + 8 * (rg >> 2) + 4 * (lane >> 5);
                if (CFG == 2 && tok >= n) continue;
                int dd = nb + j * 32 + (lane & 31);
                int c_local = dd >> (2 * lg);
                int p2 = dd & (psz * psz - 1);
                int ph = p2 >> lg, pw = p2 & (psz - 1);
                int t_ = tok >> (2 * lgo);
                int rem = tok & ((1 << (2 * lgo)) - 1);
                int oh = rem >> lgo, ow = rem & (outn - 1);
                size_t off = (((size_t)(scale * 16 + b_ * 4 + t_) * 32 + c_local) * 128
                              + ((oh << lg) + ph)) * 128 + ((ow << lg) + pw);
                attn[off] = (ushort_t)f2bf(acc[i][j][rg]);
            }
}

// fused: 4096 blocks (s0:2048, s1:1024, s2:512, s3:512)
__global__ __launch_bounds__(256) void pvm_all_kernel(
    const ushort_t* __restrict__ pbf, const ushort_t* __restrict__ vw,
    ushort_t* __restrict__ attn)
{
    const int bid = blockIdx.x;
    if (bid < 2048) {
        int sid = bid;
        pvm_dev<2>(pbf + SC_OFF0, vw, attn, 6, sid & 511, 0, sid >> 9);
    } else if (bid < 3072) {
        int sid = bid - 2048;
        pvm_dev<1>(pbf + SC_OFF1, vw, attn, 5, sid & 255, 0, sid >> 8);
    } else if (bid < 3584) {
        int sid = bid - 3072;
        pvm_dev<0>(pbf + SC_OFF2, vw, attn, 4, sid & 63, (sid >> 6) & 1, sid >> 7);
    } else {
        int sid = bid - 3584;
        pvm_dev<0>(pbf + SC_OFF3, vw, attn, 3, sid & 15, (sid >> 4) & 7, sid >> 7);
    }
}

// ---------------------------------------------------------------------------
// MFMA implicit-GEMM 3x3 conv v3: 64px x 64co waves (MFMA:LDS = 2:1), weight
// regs preloaded before stage (FIFO-safe counted vmcnt), XCD remap.
// MODE 0: outn = bf16(res + lrelu)   MODE 1: outn = bf16(lrelu)
// MODE 2: outf(NCHW f32) = res + lrelu
// grid (128, 16), block 256 (4 waves = 128px x 128co tile per h row).
// ---------------------------------------------------------------------------
template<int DIL, int MODE>
__global__ __launch_bounds__(256, 2) void conv3w_kernel(
    const ushort_t* __restrict__ in, const ushort_t* __restrict__ Wp,
    const float* __restrict__ bias, const ushort_t* __restrict__ resn,
    float* __restrict__ outf, ushort_t* __restrict__ outn,
    const ushort_t* __restrict__ zp)
{
    __shared__ ushort_t lds[17408];   // staging 2x8192 | epilogue 128x136
    const int fid = blockIdx.y * 128 + blockIdx.x;       // 0..2047
    const int nfid = (fid & 7) * 256 + (fid >> 3);       // XCD-contiguous
    const int img = nfid >> 7, h = nfid & 127;
    const int tid = threadIdx.x, lane = tid & 63, wv = tid >> 6;
    const int pxh = wv & 1, coq = wv >> 1;
    const int kch = lane >> 5;

    f32x16 acc[2][2];
    #pragma unroll
    for (int i = 0; i < 2; ++i)
        #pragma unroll
        for (int j = 0; j < 2; ++j)
            #pragma unroll
            for (int k = 0; k < 16; ++k) acc[i][j][k] = 0.f;

    auto STAGE = [&](int p, int b) {
        #pragma unroll
        for (int kb = wv; kb < 16; kb += 4) {      // exactly 4 loads per wave
            const ushort_t* src;
            if (kb == 15) {
                src = zp + lane * 8;
            } else {
                int slot = kb / 5, pg = kb % 5;
                int pxi = pg * 32 + (lane >> 1);
                int wc = pxi - 16;
                int ir = h + (slot - 1) * DIL;
                int cg = (lane & 1) ^ ((pxi >> 2) & 1);
                if (wc >= 0 && wc < 128 && ir >= 0 && ir < 128)
                    src = in + (((size_t)(img * 128 + ir)) * 8 + p) * 2048 + wc * 16 + cg * 8;
                else
                    src = zp + lane * 8;
            }
            async16(src, (char*)lds + b * 16384 + kb * 1024);
        }
    };

    STAGE(0, 0);
    #pragma unroll
    for (int p = 0; p < 8; ++p) {
        // 1) weight frags for phase p -> regs (18 VMEM, issued BEFORE prefetch)
        bf16x8 w0[9], w1[9];
        #pragma unroll
        for (int tap = 0; tap < 9; ++tap) {
            int fbase = (((p >> 1) * 9 + tap) * 2 + (p & 1)) * 4 + coq * 2;
            w0[tap] = *(const bf16x8*)(Wp + ((size_t)fbase * 64 + lane) * 8);
            w1[tap] = *(const bf16x8*)(Wp + ((size_t)(fbase + 1) * 64 + lane) * 8);
        }
        asm volatile("" ::: "memory");
        // 2) prefetch next phase's input
        if (p < 7) STAGE(p + 1, (p + 1) & 1);
        // 3) stage(p) retired; stage(p+1)+weights may remain outstanding
        if (p < 7) asm volatile("s_waitcnt vmcnt(22)" ::: "memory");
        else       asm volatile("s_waitcnt vmcnt(18)" ::: "memory");
        __builtin_amdgcn_s_barrier();
        __builtin_amdgcn_s_setprio(1);
        const ushort_t* bbuf = lds + (p & 1) * 8192;
        #pragma unroll
        for (int tap = 0; tap < 9; ++tap) {
            const int slot = tap / 3, tc = tap % 3;
            #pragma unroll
            for (int i = 0; i < 2; ++i) {
                int pxi = pxh * 64 + i * 32 + (lane & 31) + (tc - 1) * DIL + 16;
                int s = kch ^ ((pxi >> 2) & 1);
                bf16x8 bv = *(const bf16x8*)(bbuf + slot * 2560 + pxi * 16 + s * 8);
                acc[i][0] = __builtin_amdgcn_mfma_f32_32x32x16_bf16(w0[tap], bv, acc[i][0], 0, 0, 0);
                acc[i][1] = __builtin_amdgcn_mfma_f32_32x32x16_bf16(w1[tap], bv, acc[i][1], 0, 0, 0);
            }
        }
        __builtin_amdgcn_s_setprio(0);
        __builtin_amdgcn_s_barrier();
    }
    __syncthreads();

    // ---- epilogue (lds reused as [128 px][136 co-pad] bf16 tile)
    if (MODE == 0 || MODE == 2) {
        for (int u = tid; u < 2048; u += 256) {
            int px = u >> 4, c8 = (u & 15) * 8;
            size_t soff = (((size_t)(img * 128 + h)) * 8 + (c8 >> 4)) * 2048 + px * 16 + (c8 & 8);
            *(uint4*)&lds[px * 136 + c8] = *(const uint4*)&resn[soff];
        }
        __syncthreads();
    }
    #pragma unroll
    for (int i = 0; i < 2; ++i)
        #pragma unroll
        for (int tn = 0; tn < 2; ++tn)
            #pragma unroll
            for (int rg = 0; rg < 16; ++rg) {
                int co = coq * 64 + tn * 32 + (rg & 3) + 8 * (rg >> 2) + 4 * kch;
                int px = pxh * 64 + i * 32 + (lane & 31);
                float v = acc[i][tn][rg] + bias[co];
                v = (v >= 0.f) ? v : 0.2f * v;
                if (MODE == 0) {
                    float w = bf2f(lds[px * 136 + co]) + v;
                    lds[px * 136 + co] = (ushort_t)f2bf(w);
                } else if (MODE == 1) {
                    lds[px * 136 + co] = (ushort_t)f2bf(v);
                } else {
                    float w = bf2f(lds[px * 136 + co]) + v;
                    outf[(((size_t)(img * 128 + co)) * 128 + h) * 128 + px] = w;
                }
            }
    if (MODE == 0 || MODE == 1) {
        __syncthreads();
        for (int u = tid; u < 2048; u += 256) {
            int px = u >> 4, c8 = (u & 15) * 8;
            size_t doff = (((size_t)(img * 128 + h)) * 8 + (c8 >> 4)) * 2048 + px * 16 + (c8 & 8);
            *(uint4*)&outn[doff] = *(const uint4*)&lds[px * 136 + c8];
        }
    }
}

// ---------------------------------------------------------------------------
extern "C" void kernel_launch(void* const* d_in, const int* in_sizes, int n_in,
                              void* d_out, int out_size, void* d_ws, size_t ws_size,
                              hipStream_t stream)
{
    const float* x   = (const float*)d_in[0];
    const float* Wq  = (const float*)d_in[1];
    const float* bq  = (const float*)d_in[2];
    const float* Wk  = (const float*)d_in[3];
    const float* bk  = (const float*)d_in[4];
    const float* Wv  = (const float*)d_in[5];
    const float* bv  = (const float*)d_in[6];
    const float* Wo  = (const float*)d_in[7];
    const float* bo  = (const float*)d_in[8];
    const float* Wf1 = (const float*)d_in[9];
    const float* bf1 = (const float*)d_in[10];
    const float* Wf2 = (const float*)d_in[11];
    const float* bf2 = (const float*)d_in[12];
    float* out = (float*)d_out;
    char* ws = (char*)d_ws;
    const size_t MB = 1048576ull;
    ushort_t* qw   = (ushort_t*)(ws);                 // 64 MB; attnc alias; later ff1n
    ushort_t* kw   = (ushort_t*)(ws + 64 * MB);       // 64 MB; later attn NHWC-p
    ushort_t* vw   = (ushort_t*)(ws + 128 * MB);      // 64 MB; V transposed; later x1n
    ushort_t* xn   = (ushort_t*)(ws + 192 * MB);      // 64 MB; x NHWC-p (lives to conv1)
    float*    sc   = (float*)   (ws + 256 * MB);      // 17.9 MB
    ushort_t* Wp   = (ushort_t*)(ws + 274 * MB);      // 864 KB
    ushort_t* Wqkv = (ushort_t*)(ws + 275 * MB);      // 96 KB
    ushort_t* zp   = (ushort_t*)(ws + 275 * MB + 256 * 1024);  // 1 KB zeros
    ushort_t* pbf  = (ushort_t*)(ws + 276 * MB);      // 8.95 MB
    ushort_t* attnc = qw;
    ushort_t* nhwc  = kw;
    ushort_t* x1n   = vw;
    ushort_t* ff1n  = qw;

    hipMemsetAsync(zp, 0, 1024, stream);
    // zero the atomicAdd score regions (s0/s1/s2): contiguous tail after s3
    hipMemsetAsync(sc + SC_OFF2, 0, (size_t)(SC_TOT - SC_OFF2) * 4, stream);
    prepack_kernel<<<dim3(576, 3), 256, 0, stream>>>(Wo, Wf1, Wf2, Wp);
    prepack1_kernel<<<dim3(64, 3), 256, 0, stream>>>(Wq, Wk, Wv, Wqkv);

    // 1) x -> NHWC-p, then q/k/v (V scattered directly transposed)
    nchw2nhwc_kernel<<<dim3(128, 16), 256, 0, stream>>>(x, xn);
    qkvm_kernel<<<dim3(64, 16, 3), 256, 0, stream>>>(xn, Wqkv, bq, bk, bv, qw, kw, vw);

    // 2) attention: 3 fused launches over all 4 scales
    scores_all_kernel<<<dim3(1024), 256, 0, stream>>>(qw, kw, sc);
    softmax_all_kernel<<<dim3(5440), 256, 0, stream>>>(sc, pbf);
    pvm_all_kernel<<<dim3(4096), 256, 0, stream>>>(pbf, vw, attnc);

    // 3) attn chunks -> NHWC-p
    attn2nhwc_kernel<<<dim3(128, 16), 256, 0, stream>>>(attnc, nhwc);
    // 4) x1 = x + lrelu(conv3x3(attn)) -> x1n NHWC-p
    conv3w_kernel<1, 0><<<dim3(128, 16), 256, 0, stream>>>(nhwc, Wp, bo, xn, nullptr, x1n, zp);
    // 5) ff1 = lrelu(conv3x3 dil2(x1)) -> ff1n NHWC-p
    conv3w_kernel<2, 1><<<dim3(128, 16), 256, 0, stream>>>(x1n, Wp + 147456, bf1, nullptr, nullptr, ff1n, zp);
    // 6) out = x1 + lrelu(conv3x3(ff1)) -> d_out fp32 NCHW
    conv3w_kernel<1, 2><<<dim3(128, 16), 256, 0, stream>>>(ff1n, Wp + 2 * 147456, bf2, x1n, out, nullptr, zp);
}